// Round 6
// baseline (240.662 us; speedup 1.0000x reference)
//
#include <hip/hip_runtime.h>
#include <math.h>

// GATv2 (in_ch=1, edge_dim=1, H=2, C=64) + fc, collapsed to rank-1/rank-2 algebra.
//
// Round 6: counting-sort into a FIXED-CAPACITY cell matrix — no scans, no
// binary searches, no global atomics on the hot path.
//   k_bin   : 782 blocks x 2048 edges; payload -> rec cell (bucket-major:
//             rec[(b*SB+s)*cap+slot]), slot from LDS counter; writes 196B count row.
//   k_reduce: 392 blocks (196 buckets x 2 splits); streams its half of the
//             bucket's contiguous cell region; 6 LDS atomics/record into
//             512x7 accum; packed partial out.
//   k_final : merge 2 partials + overflow acc + self-loop softmax -> S.
//   k_out   : rank-2 output expansion (51MB write).
//
// ws: rec[NB*SB*cap] int4 | cntm[SB*256] u8 | part[NB*2*512*6] f32 |
//     acc[8N] f32 (memset 0, overflow fallback) | S[2N] | C[1152]

#define LRELU_A1 0.6f   // leakyrelu(v) = 0.6 v + 0.4 |v|  (slope 0.2)
#define LRELU_A2 0.4f
#define NPB       512   // nodes per bucket (dst>>9)
#define NPB_SHIFT 9
#define EPB      2048   // edges per bin block
#define TB_BIN    512
#define CAP_MAX    24

__global__ void k_prep(const unsigned int* __restrict__ ei,
                       const float* __restrict__ att,
                       const float* __restrict__ W_l,
                       const float* __restrict__ b_l, const float* __restrict__ b_r,
                       const float* __restrict__ bias_out,
                       const float* __restrict__ W_fc, const float* __restrict__ b_fc,
                       float* __restrict__ C) {
  int j = threadIdx.x;
  unsigned long long nz = __ballot(j < 32 && ei[2 * j + 1] != 0u);
  if (j == 0) ((int*)C)[1024] = (nz == 0ull) ? 1 : 0;   // 1 => int64 indices
  if (j >= 128) return;
  float a = att[j];
  C[j] = LRELU_A1 * a;          // A1
  C[128 + j] = LRELU_A2 * a;    // A2
  C[256 + j] = b_l[j] + b_r[j]; // BASE
  const float* wrow = W_fc + j * 256;
  float u0 = 0.f, u1 = 0.f, v0 = 0.f, v1 = 0.f, cb = b_fc[j];
  for (int c = 0; c < 64; c++) {
    u0 = fmaf(W_l[c],      wrow[c],       u0);
    u1 = fmaf(W_l[64 + c], wrow[64 + c],  u1);
    v0 = fmaf(W_l[c],      wrow[128 + c], v0);
    v1 = fmaf(W_l[64 + c], wrow[192 + c], v1);
  }
  for (int t = 0; t < 128; t++) {
    float gb = b_l[t] + bias_out[t];
    cb = fmaf(gb, wrow[t] + wrow[128 + t], cb);
  }
  C[384 + j] = u0;  // U0
  C[512 + j] = u1;  // U1
  C[640 + j] = v0;  // V0
  C[768 + j] = v1;  // V1
  C[896 + j] = cb;  // CB
}

#define CH_STEP(comp, ACC, i)                                                      \
  do {                                                                             \
    float v_ = fmaf(xs4[i], wl.comp, fmaf(xt4[i], wr.comp, fmaf(ae4[i], we.comp, bb.comp))); \
    ACC[i] = fmaf(a2.comp, fabsf(v_), fmaf(a1.comp, v_, ACC[i]));                  \
  } while (0)

__global__ __launch_bounds__(TB_BIN) void k_bin(
    const float* __restrict__ x, const int* __restrict__ ei,
    const float* __restrict__ ea,
    const float* __restrict__ WL, const float* __restrict__ WR,
    const float* __restrict__ WE, const float* __restrict__ C,
    int4* __restrict__ rec, unsigned char* __restrict__ cntm,
    float* __restrict__ acc, int cap, int NB, int SB, int E) {
  __shared__ int cnt[256];
  const int tid = threadIdx.x;
  if (tid < 256) cnt[tid] = 0;
  __syncthreads();

  const int e0 = blockIdx.x * EPB;
  const bool w64 = ((const int*)C)[1024] != 0;
  const float* A1 = C;
  const float* A2 = C + 128;
  const float* BASE = C + 256;

  int de4[4];
  float ae4[4], xs4[4], xt4[4];
  bool ok[4];
#pragma unroll
  for (int i = 0; i < 4; i++) {
    int e = e0 + i * TB_BIN + tid;   // coalesced per round
    ok[i] = (e < E);
    int ee = ok[i] ? e : 0;
    int s_ = w64 ? ei[2 * ee] : ei[ee];
    int d_ = w64 ? ei[2 * (E + ee)] : ei[E + ee];
    de4[i] = d_;
    ae4[i] = ea[ee];
    xs4[i] = x[s_];
    xt4[i] = x[d_];
  }
  float acc0[4] = {0.f, 0.f, 0.f, 0.f};
  float acc1[4] = {0.f, 0.f, 0.f, 0.f};
#pragma unroll 4
  for (int jb = 0; jb < 64; jb += 4) {
    float4 wl = *(const float4*)(WL + jb);
    float4 wr = *(const float4*)(WR + jb);
    float4 we = *(const float4*)(WE + jb);
    float4 bb = *(const float4*)(BASE + jb);
    float4 a1 = *(const float4*)(A1 + jb);
    float4 a2 = *(const float4*)(A2 + jb);
#pragma unroll
    for (int i = 0; i < 4; i++) {
      CH_STEP(x, acc0, i); CH_STEP(y, acc0, i); CH_STEP(z, acc0, i); CH_STEP(w, acc0, i);
    }
  }
#pragma unroll 4
  for (int jb = 64; jb < 128; jb += 4) {
    float4 wl = *(const float4*)(WL + jb);
    float4 wr = *(const float4*)(WR + jb);
    float4 we = *(const float4*)(WE + jb);
    float4 bb = *(const float4*)(BASE + jb);
    float4 a1 = *(const float4*)(A1 + jb);
    float4 a2 = *(const float4*)(A2 + jb);
#pragma unroll
    for (int i = 0; i < 4; i++) {
      CH_STEP(x, acc1, i); CH_STEP(y, acc1, i); CH_STEP(z, acc1, i); CH_STEP(w, acc1, i);
    }
  }
#pragma unroll
  for (int i = 0; i < 4; i++) {
    if (!ok[i]) continue;
    int d_ = de4[i];
    int b = d_ >> NPB_SHIFT;
    float eh0 = __expf(acc0[i]);
    float eh1 = __expf(acc1[i]);
    int slot = atomicAdd(&cnt[b], 1);
    if (slot < cap) {
      unsigned eab = (__float_as_uint(ae4[i]) & ~511u) | (unsigned)(d_ & 511);
      rec[((size_t)b * SB + blockIdx.x) * cap + slot] =
          make_int4(__float_as_int(eh0), __float_as_int(eh1),
                    __float_as_int(xs4[i]), (int)eab);
    } else {  // rare overflow: global-atomic fallback
      float* a = acc + (size_t)d_ * 8;
      atomicAdd(a + 0, eh0);
      atomicAdd(a + 1, eh0 * xs4[i]);
      atomicAdd(a + 2, eh1);
      atomicAdd(a + 3, eh1 * xs4[i]);
      atomicAdd(a + 4, ae4[i]);
      atomicAdd(a + 5, 1.0f);
    }
  }
  __syncthreads();
  // write clamped counts as a contiguous 256B row (u8), 4 per u32 word
  if (tid < 64) {
    unsigned w = 0;
#pragma unroll
    for (int k = 0; k < 4; k++) {
      int b = tid * 4 + k;
      unsigned c = (unsigned)min(cnt[b], cap);
      w |= (c & 0xFFu) << (8 * k);
    }
    ((unsigned*)(cntm + (size_t)blockIdx.x * 256))[tid] = w;
  }
}

__global__ __launch_bounds__(256, 4) void k_reduce(
    const int4* __restrict__ rec, const unsigned char* __restrict__ cntm,
    float* __restrict__ part, int cap, int SB) {
  __shared__ float lacc[NPB * 7];      // stride 7, bank-friendly
  const int tid = threadIdx.x;
  const int b = blockIdx.x >> 1;
  const int j = blockIdx.x & 1;
  for (int i = tid; i < NPB * 7; i += 256) lacc[i] = 0.f;
  __syncthreads();
  const int sh = (SB + 1) >> 1;
  const int s_end = min(SB, (j + 1) * sh);
  for (int s = j * sh + tid; s < s_end; s += 256) {
    int c = cntm[(size_t)s * 256 + b];
    const int4* cell = rec + ((size_t)b * SB + s) * cap;
    for (int i = 0; i < c; i++) {
      int4 r = cell[i];
      float e0v = __int_as_float(r.x);
      float e1v = __int_as_float(r.y);
      float xsv = __int_as_float(r.z);
      unsigned eab = (unsigned)r.w;
      float* a = lacc + (int)(eab & 511u) * 7;
      float aev = __uint_as_float(eab & ~511u);
      atomicAdd(a + 0, e0v);
      atomicAdd(a + 1, e0v * xsv);
      atomicAdd(a + 2, e1v);
      atomicAdd(a + 3, e1v * xsv);
      atomicAdd(a + 4, aev);
      atomicAdd(a + 5, 1.0f);
    }
  }
  __syncthreads();
  float* dst = part + (size_t)blockIdx.x * (NPB * 6);
  for (int i = tid; i < NPB * 6; i += 256)
    dst[i] = lacc[(i / 6) * 7 + (i % 6)];
}

__global__ __launch_bounds__(256) void k_final(
    const float* __restrict__ x,
    const float* __restrict__ WL, const float* __restrict__ WR,
    const float* __restrict__ WE, const float* __restrict__ C,
    const float* __restrict__ part, const float* __restrict__ acc,
    float* __restrict__ S, int N) {
  int n = blockIdx.x * blockDim.x + threadIdx.x;
  if (n >= N) return;
  int b = n >> NPB_SHIFT;
  int l = n & (NPB - 1);
  const float* p0 = part + ((size_t)(2 * b)     * (NPB * 6)) + l * 6;
  const float* p1 = part + ((size_t)(2 * b + 1) * (NPB * 6)) + l * 6;
  const float* g  = acc + (size_t)n * 8;
  float den0 = p0[0] + p1[0] + g[0];
  float num0 = p0[1] + p1[1] + g[1];
  float den1 = p0[2] + p1[2] + g[2];
  float num1 = p0[3] + p1[3] + g[3];
  float asum = p0[4] + p1[4] + g[4];
  float cntv = p0[5] + p1[5] + g[5];
  const float* A1 = C;
  const float* A2 = C + 128;
  const float* BASE = C + 256;
  float xn = x[n];
  float am = asum / fmaxf(cntv, 1.0f);
  float acc0 = 0.f, acc1 = 0.f;
#pragma unroll 4
  for (int jb = 0; jb < 64; jb += 4) {
    float4 wl = *(const float4*)(WL + jb);
    float4 wr = *(const float4*)(WR + jb);
    float4 we = *(const float4*)(WE + jb);
    float4 bb = *(const float4*)(BASE + jb);
    float4 a1 = *(const float4*)(A1 + jb);
    float4 a2 = *(const float4*)(A2 + jb);
    float v;
    v = fmaf(xn, wl.x + wr.x, fmaf(am, we.x, bb.x)); acc0 = fmaf(a2.x, fabsf(v), fmaf(a1.x, v, acc0));
    v = fmaf(xn, wl.y + wr.y, fmaf(am, we.y, bb.y)); acc0 = fmaf(a2.y, fabsf(v), fmaf(a1.y, v, acc0));
    v = fmaf(xn, wl.z + wr.z, fmaf(am, we.z, bb.z)); acc0 = fmaf(a2.z, fabsf(v), fmaf(a1.z, v, acc0));
    v = fmaf(xn, wl.w + wr.w, fmaf(am, we.w, bb.w)); acc0 = fmaf(a2.w, fabsf(v), fmaf(a1.w, v, acc0));
  }
#pragma unroll 4
  for (int jb = 64; jb < 128; jb += 4) {
    float4 wl = *(const float4*)(WL + jb);
    float4 wr = *(const float4*)(WR + jb);
    float4 we = *(const float4*)(WE + jb);
    float4 bb = *(const float4*)(BASE + jb);
    float4 a1 = *(const float4*)(A1 + jb);
    float4 a2 = *(const float4*)(A2 + jb);
    float v;
    v = fmaf(xn, wl.x + wr.x, fmaf(am, we.x, bb.x)); acc1 = fmaf(a2.x, fabsf(v), fmaf(a1.x, v, acc1));
    v = fmaf(xn, wl.y + wr.y, fmaf(am, we.y, bb.y)); acc1 = fmaf(a2.y, fabsf(v), fmaf(a1.y, v, acc1));
    v = fmaf(xn, wl.z + wr.z, fmaf(am, we.z, bb.z)); acc1 = fmaf(a2.z, fabsf(v), fmaf(a1.z, v, acc1));
    v = fmaf(xn, wl.w + wr.w, fmaf(am, we.w, bb.w)); acc1 = fmaf(a2.w, fabsf(v), fmaf(a1.w, v, acc1));
  }
  float s0 = __expf(acc0), s1 = __expf(acc1);
  float2 sv;
  sv.x = (num0 + s0 * xn) / (den0 + s0);
  sv.y = (num1 + s1 * xn) / (den1 + s1);
  *(float2*)(S + 2 * n) = sv;
}

__global__ __launch_bounds__(256) void k_out(
    const float* __restrict__ S, const float* __restrict__ C,
    const int* __restrict__ tgtp, float* __restrict__ out, int N) {
  int g = blockIdx.x * blockDim.x + threadIdx.x;
  if (g >= N * 32) return;
  int n = g >> 5;
  int kq = (g & 31) * 4;
  int T = tgtp[0];  // low word valid for int32 and little-endian int64
  float s0t = S[2 * T], s1t = S[2 * T + 1];
  float2 s = *(const float2*)(S + 2 * n);
  float4 u0 = *(const float4*)(C + 384 + kq);
  float4 u1 = *(const float4*)(C + 512 + kq);
  float4 v0 = *(const float4*)(C + 640 + kq);
  float4 v1 = *(const float4*)(C + 768 + kq);
  float4 cb = *(const float4*)(C + 896 + kq);
  float4 o;
  o.x = fmaf(s.x, u0.x, fmaf(s.y, u1.x, fmaf(s0t, v0.x, fmaf(s1t, v1.x, cb.x))));
  o.y = fmaf(s.x, u0.y, fmaf(s.y, u1.y, fmaf(s0t, v0.y, fmaf(s1t, v1.y, cb.y))));
  o.z = fmaf(s.x, u0.z, fmaf(s.y, u1.z, fmaf(s0t, v0.z, fmaf(s1t, v1.z, cb.z))));
  o.w = fmaf(s.x, u0.w, fmaf(s.y, u1.w, fmaf(s0t, v0.w, fmaf(s1t, v1.w, cb.w))));
  *(float4*)(out + n * 128 + kq) = o;
}

extern "C" void kernel_launch(void* const* d_in, const int* in_sizes, int n_in,
                              void* d_out, int out_size, void* d_ws, size_t ws_size,
                              hipStream_t stream) {
  const float* x        = (const float*)d_in[0];
  const int*   ei       = (const int*)d_in[1];
  const float* ea       = (const float*)d_in[2];
  const int*   tgt      = (const int*)d_in[3];
  const float* W_l      = (const float*)d_in[4];
  const float* b_l      = (const float*)d_in[5];
  const float* W_r      = (const float*)d_in[6];
  const float* b_r      = (const float*)d_in[7];
  const float* W_e      = (const float*)d_in[8];
  const float* att      = (const float*)d_in[9];
  const float* bias_out = (const float*)d_in[10];
  const float* W_fc     = (const float*)d_in[11];
  const float* b_fc     = (const float*)d_in[12];

  const int N = in_sizes[0];
  const int E = in_sizes[2];
  const int NB = (N + NPB - 1) / NPB;          // 196 buckets (assumes <= 256)
  const int SB = (E + EPB - 1) / EPB;          // 782 bin blocks

  // fixed-region sizes
  size_t cnt_bytes  = (size_t)SB * 256;                    // u8 count matrix
  size_t part_bytes = (size_t)NB * 2 * NPB * 6 * 4;        // partials
  size_t acc_bytes  = (size_t)N * 8 * 4;                   // overflow fallback
  size_t S_bytes    = (size_t)N * 2 * 4;
  size_t C_bytes    = 1152 * 4;
  size_t fixed = cnt_bytes + part_bytes + acc_bytes + S_bytes + C_bytes + 1024;

  int cap = 1;
  if (ws_size > fixed) {
    size_t c = (ws_size - fixed) / ((size_t)NB * SB * 16);
    cap = (int)(c > CAP_MAX ? CAP_MAX : (c < 1 ? 1 : c));
  }

  char* p = (char*)d_ws;
  int4*          rec  = (int4*)p;          p += (size_t)NB * SB * cap * 16;
  unsigned char* cntm = (unsigned char*)p; p += cnt_bytes;
  float*         part = (float*)p;         p += part_bytes;
  float*         acc  = (float*)p;         p += acc_bytes;
  float*         S    = (float*)p;         p += S_bytes;
  float*         C    = (float*)p;

  hipMemsetAsync(acc, 0, acc_bytes, stream);
  k_prep<<<1, 128, 0, stream>>>((const unsigned int*)ei, att, W_l, b_l, b_r,
                                bias_out, W_fc, b_fc, C);
  k_bin<<<SB, TB_BIN, 0, stream>>>(x, ei, ea, W_l, W_r, W_e, C,
                                   rec, cntm, acc, cap, NB, SB, E);
  k_reduce<<<NB * 2, 256, 0, stream>>>(rec, cntm, part, cap, SB);
  k_final<<<(N + 255) / 256, 256, 0, stream>>>(x, W_l, W_r, W_e, C, part, acc, S, N);
  k_out<<<(N * 32 + 255) / 256, 256, 0, stream>>>(S, C, tgt, (float*)d_out, N);
}